// Round 17
// baseline (476.411 us; speedup 1.0000x reference)
//
#include <hip/hip_runtime.h>
#include <hip/hip_fp8.h>
#include <stdint.h>

typedef _Float16 f16x8 __attribute__((ext_vector_type(8)));
typedef _Float16 f16x2 __attribute__((ext_vector_type(2)));
typedef float f32x4 __attribute__((ext_vector_type(4)));
typedef float f32x2 __attribute__((ext_vector_type(2)));

__device__ __forceinline__ unsigned short f2h(float f) {
    _Float16 h = (_Float16)f;
    return __builtin_bit_cast(unsigned short, h);
}
__device__ __forceinline__ float h2f(unsigned short s) {
    _Float16 h = __builtin_bit_cast(_Float16, s);
    return (float)h;
}

// fp8 e4m3 (OCP on gfx950) encode/decode
__device__ __forceinline__ unsigned pack_q4(float f0, float f1, float f2, float f3) {
#if __has_builtin(__builtin_amdgcn_cvt_pk_fp8_f32)
    unsigned u = (unsigned)__builtin_amdgcn_cvt_pk_fp8_f32(f0, f1, 0, false);
    u = (unsigned)__builtin_amdgcn_cvt_pk_fp8_f32(f2, f3, u, true);
    return u;
#else
    __hip_fp8_e4m3 q0(f0), q1(f1), q2(f2), q3(f3);
    return (unsigned)q0.__x | ((unsigned)q1.__x << 8) |
           ((unsigned)q2.__x << 16) | ((unsigned)q3.__x << 24);
#endif
}
__device__ __forceinline__ void add_q8(float* a, uint2 v, float s) {
#if __has_builtin(__builtin_amdgcn_cvt_pk_f32_fp8)
    f32x2 p0 = __builtin_amdgcn_cvt_pk_f32_fp8(v.x, false);
    f32x2 p1 = __builtin_amdgcn_cvt_pk_f32_fp8(v.x, true);
    f32x2 p2 = __builtin_amdgcn_cvt_pk_f32_fp8(v.y, false);
    f32x2 p3 = __builtin_amdgcn_cvt_pk_f32_fp8(v.y, true);
    a[0] += s * p0[0]; a[1] += s * p0[1];
    a[2] += s * p1[0]; a[3] += s * p1[1];
    a[4] += s * p2[0]; a[5] += s * p2[1];
    a[6] += s * p3[0]; a[7] += s * p3[1];
#else
    unsigned char b[8];
    *(uint2*)b = v;
    #pragma unroll
    for (int j = 0; j < 8; j++) {
        __hip_fp8_e4m3 q; q.__x = b[j];
        a[j] += s * (float)q;
    }
#endif
}

__device__ __forceinline__ void gload16(const void* g, void* lds) {
    __builtin_amdgcn_global_load_lds(
        (const __attribute__((address_space(1))) void*)g,
        (__attribute__((address_space(3))) void*)lds, 16, 0, 0);
}

#if __has_builtin(__builtin_amdgcn_fdot2)
__device__ __forceinline__ float dot2(f16x2 a, f16x2 b, float c) {
    return __builtin_amdgcn_fdot2(a, b, c, false);
}
#else
__device__ __forceinline__ float dot2(f16x2 a, f16x2 b, float c) {
    return c + (float)a[0] * (float)b[0] + (float)a[1] * (float)b[1];
}
#endif

// ---------------- fused prep: x f32->fp16 (padded), W stack f32->fp16, edge histogram
__global__ __launch_bounds__(256) void k_prep(
    const float* __restrict__ x, unsigned short* __restrict__ xf,
    size_t valid, size_t total,
    const float* __restrict__ Wb, const float* __restrict__ Wv,
    const float* __restrict__ Wc, unsigned short* __restrict__ Wf,
    const int* __restrict__ eb, const int* __restrict__ ev, const int* __restrict__ ec,
    int Eb, int Ev, int Ec, int* __restrict__ cnt, int N)
{
    size_t i = (size_t)blockIdx.x * 256 + threadIdx.x;
    size_t idx = i * 4;
    if (idx < total) {
        ushort4 h;
        if (idx < valid) {
            float4 f = *(const float4*)(x + idx);
            h.x = f2h(f.x); h.y = f2h(f.y); h.z = f2h(f.z); h.w = f2h(f.w);
        } else {
            h.x = h.y = h.z = h.w = 0;
        }
        *(ushort4*)(xf + idx) = h;
    }
    if (idx < (size_t)1536 * 512) {
        int m = (int)(idx >> 9), k = (int)(idx & 511);
        const float* src;
        if (m < 512)       src = Wb + (size_t)m * 512 + k;
        else if (m < 1024) src = Wv + (size_t)(m - 512) * 512 + k;
        else               src = Wc + (size_t)(m - 1024) * 512 + k;
        float4 f = *(const float4*)src;
        ushort4 h;
        h.x = f2h(f.x); h.y = f2h(f.y); h.z = f2h(f.z); h.w = f2h(f.w);
        *(ushort4*)(Wf + idx) = h;
    }
    if (i < (size_t)(Eb + Ev + Ec)) {
        int ii = (int)i;
        if (ii < Eb) atomicAdd(cnt + eb[ii], 1);
        else if (ii < Eb + Ev) atomicAdd(cnt + N + ev[ii - Eb], 1);
        else atomicAdd(cnt + 2 * N + ec[ii - Eb - Ev], 1);
    }
}

// ---------------- CSR scans / scatter ----------------
__global__ __launch_bounds__(256) void k_scan_a(
    const int* __restrict__ cnt, int* __restrict__ ptr, int* __restrict__ bsum, int M)
{
    __shared__ int sh[256];
    int t = threadIdx.x;
    int base = blockIdx.x * 1024 + t * 4;
    int v[4];
    #pragma unroll
    for (int j = 0; j < 4; j++) v[j] = (base + j < M) ? cnt[base + j] : 0;
    int local = v[0] + v[1] + v[2] + v[3];
    sh[t] = local; __syncthreads();
    #pragma unroll
    for (int off = 1; off < 256; off <<= 1) {
        int x = (t >= off) ? sh[t - off] : 0;
        __syncthreads();
        sh[t] += x;
        __syncthreads();
    }
    int run = sh[t] - local;
    #pragma unroll
    for (int j = 0; j < 4; j++) {
        if (base + j < M) ptr[base + j] = run;
        run += v[j];
    }
    if (t == 255) bsum[blockIdx.x] = sh[255];
}

// scan_c with scan_b folded in: every block redundantly scans bsum (nb<=256)
__global__ __launch_bounds__(256) void k_scan_c(
    int* __restrict__ ptr, const int* __restrict__ bsum, int* __restrict__ cur,
    const int* __restrict__ cnt, float* __restrict__ dinv,
    int M, int N, int total, int nb)
{
    __shared__ int raw[256], scn[256];
    int t = threadIdx.x;
    int v = (t < nb) ? bsum[t] : 0;
    raw[t] = v; scn[t] = v; __syncthreads();
    #pragma unroll
    for (int off = 1; off < 256; off <<= 1) {
        int x = (t >= off) ? scn[t - off] : 0;
        __syncthreads();
        scn[t] += x;
        __syncthreads();
    }
    int idx = blockIdx.x * 256 + t;
    if (idx < M) {
        int blk = idx >> 10;
        int p = ptr[idx] + (scn[blk] - raw[blk]);   // exclusive block offset
        ptr[idx] = p;
        cur[idx] = p;
        if (idx < N) dinv[idx] = rsqrtf((float)(cnt[idx] + 1));
    }
    if (idx == 0) ptr[M] = total;
}

__global__ __launch_bounds__(256) void k_scatter3(
    const int* __restrict__ eb, const int* __restrict__ ev, const int* __restrict__ ec,
    int Eb, int Ev, int Ec, int* __restrict__ cur, int* __restrict__ cidx, int N)
{
    int i = blockIdx.x * 256 + threadIdx.x;
    const int* e; int il, off, E;
    if (i < Eb) { e = eb; il = i; off = 0; E = Eb; }
    else if (i < Eb + Ev) { e = ev; il = i - Eb; off = N; E = Ev; }
    else if (i < Eb + Ev + Ec) { e = ec; il = i - Eb - Ev; off = 2 * N; E = Ec; }
    else return;
    int r = e[il], c = e[E + il];
    int pos = atomicAdd(cur + off + r, 1);
    cidx[pos] = c;
}

// ---------------- UNIFIED fp16 GEMM: 128x128 tile, 4 waves, BK=64.
// A: double-buffered global_load_lds (32 KB total). B: L2-resident W panel
// loaded DIRECTLY into registers with 1-step prefetch (no LDS, no barrier
// coupling). vmcnt(12) covers both A-cur (4 gloads) and B-cur (8 loads).
// Swapped-operand MFMA + packed epilogue (R16).
__global__ __launch_bounds__(256) void k_gemm_f(
    const unsigned short* __restrict__ xf, const unsigned short* __restrict__ Wf,
    const float* __restrict__ dinv, int N,
    unsigned char* __restrict__ Ybv, unsigned short* __restrict__ Ycf)
{
    __shared__ uint4 As[2][1024];   // 2 x (128 rows x 8 chunks)

    const int id = blockIdx.x;
    const int xcd = id & 7;
    const int jj = id >> 3;
    const int bn = jj % 12;
    const int bm = xcd + 8 * (jj / 12);

    const int t = threadIdx.x;
    const int lane = t & 63;
    const int w = t >> 6;            // 0..3
    const int wr = w >> 1;           // 0..1
    const int wc = w & 1;            // 0..1
    const int rA = lane >> 3;
    const int cs = lane & 7;

    f32x4 acc[4][4];
    #pragma unroll
    for (int i = 0; i < 4; i++)
        #pragma unroll
        for (int j = 0; j < 4; j++) acc[i][j] = (f32x4){0.f, 0.f, 0.f, 0.f};

    const size_t baseA = (size_t)bm * 128 * 512;
    const int cg = cs ^ rA;

    // per-lane B fragment base: row = bn*128 + wc*64 + (lane&15), chunk base (lane>>4)*8
    const unsigned short* bbase =
        Wf + ((size_t)bn * 128 + wc * 64 + (lane & 15)) * 512 + (lane >> 4) * 8;

    // prologue: A tile 0 -> As[0]; B frags step 0 -> b0
    #pragma unroll
    for (int j = 0; j < 4; j++) {
        int seg = w * 4 + j;
        int r = seg * 8 + rA;
        gload16(xf + baseA + (size_t)r * 512 + cg * 8, &As[0][seg * 64]);
    }
    f16x8 b0[2][4], b1[2][4];
    #pragma unroll
    for (int kk = 0; kk < 2; kk++)
        #pragma unroll
        for (int mi = 0; mi < 4; mi++)
            b0[kk][mi] = *(const f16x8*)(bbase + (size_t)mi * 8192 + kk * 32);

    #pragma unroll
    for (int s = 0; s < 8; ++s) {
        const int cur = s & 1;
        f16x8 (&bc)[2][4] = (s & 1) ? b1 : b0;   // current regs
        f16x8 (&bnx)[2][4] = (s & 1) ? b0 : b1;  // next regs
        if (s < 7) {
            const int kt = (s + 1) * 64;
            #pragma unroll
            for (int j = 0; j < 4; j++) {
                int seg = w * 4 + j;
                int r = seg * 8 + rA;
                gload16(xf + baseA + (size_t)r * 512 + kt + cg * 8, &As[cur ^ 1][seg * 64]);
            }
            #pragma unroll
            for (int kk = 0; kk < 2; kk++)
                #pragma unroll
                for (int mi = 0; mi < 4; mi++)
                    bnx[kk][mi] = *(const f16x8*)(bbase + (size_t)mi * 8192 + kt + kk * 32);
            asm volatile("s_waitcnt vmcnt(12)" ::: "memory");
        } else {
            asm volatile("s_waitcnt vmcnt(0)" ::: "memory");
        }
        __builtin_amdgcn_sched_barrier(0);
        __builtin_amdgcn_s_barrier();   // A-cur staged by all waves

        #pragma unroll
        for (int kk = 0; kk < 2; kk++) {
            f16x8 a[4];
            #pragma unroll
            for (int ni = 0; ni < 4; ni++) {
                int ar = wr * 64 + ni * 16 + (lane & 15);
                int k8 = kk * 4 + (lane >> 4);
                a[ni] = __builtin_bit_cast(f16x8, As[cur][ar * 8 + (k8 ^ (ar & 7))]);
            }
            #pragma unroll
            for (int mi = 0; mi < 4; mi++)
                #pragma unroll
                for (int ni = 0; ni < 4; ni++)
                    acc[mi][ni] = __builtin_amdgcn_mfma_f32_16x16x32_f16(
                        bc[kk][mi], a[ni], acc[mi][ni], 0, 0, 0);
        }
        asm volatile("s_waitcnt lgkmcnt(0)" ::: "memory");
        __builtin_amdgcn_sched_barrier(0);
        __builtin_amdgcn_s_barrier();   // ds_reads done before buffer overwrite
    }

    // epilogue: n carries a-dim (lane&15 + ni*16), m carries b-dim quads
    const int nbase = bm * 128 + wr * 64 + (lane & 15);
    const int mq = wc * 64 + (lane >> 4) * 4;
    if (bn < 4) {
        #pragma unroll
        for (int ni = 0; ni < 4; ni++) {
            int n = nbase + ni * 16;
            float dv = (n < N) ? dinv[n] : 0.f;
            #pragma unroll
            for (int mi = 0; mi < 4; mi++) {
                int m0 = bn * 128 + mq + mi * 16;
                unsigned u = pack_q4(acc[mi][ni][0] * dv, acc[mi][ni][1] * dv,
                                     acc[mi][ni][2] * dv, acc[mi][ni][3] * dv);
                *(unsigned*)(Ybv + (size_t)n * 1024 + m0) = u;
            }
        }
    } else if (bn < 8) {
        #pragma unroll
        for (int ni = 0; ni < 4; ni++) {
            int n = nbase + ni * 16;
            #pragma unroll
            for (int mi = 0; mi < 4; mi++) {
                int m0 = bn * 128 + mq + mi * 16;
                unsigned u = pack_q4(acc[mi][ni][0], acc[mi][ni][1],
                                     acc[mi][ni][2], acc[mi][ni][3]);
                *(unsigned*)(Ybv + (size_t)n * 1024 + m0) = u;
            }
        }
    } else {
        #pragma unroll
        for (int ni = 0; ni < 4; ni++) {
            int n = nbase + ni * 16;
            #pragma unroll
            for (int mi = 0; mi < 4; mi++) {
                int m0 = (bn - 8) * 128 + mq + mi * 16;
                ushort4 h;
                h.x = f2h(acc[mi][ni][0]); h.y = f2h(acc[mi][ni][1]);
                h.z = f2h(acc[mi][ni][2]); h.w = f2h(acc[mi][ni][3]);
                *(ushort4*)(Ycf + (size_t)n * 512 + m0) = h;
            }
        }
    }
}

// ---------------- fused gather: one wave per node; chunk-8 on fp8 paths
__device__ __forceinline__ void acc_h8(float* a, uint4 v, float s) {
    a[0] += s * h2f((unsigned short)(v.x & 0xffff));
    a[1] += s * h2f((unsigned short)(v.x >> 16));
    a[2] += s * h2f((unsigned short)(v.y & 0xffff));
    a[3] += s * h2f((unsigned short)(v.y >> 16));
    a[4] += s * h2f((unsigned short)(v.z & 0xffff));
    a[5] += s * h2f((unsigned short)(v.z >> 16));
    a[6] += s * h2f((unsigned short)(v.w & 0xffff));
    a[7] += s * h2f((unsigned short)(v.w >> 16));
}
__device__ __forceinline__ float dot8(const f16x2* ph, uint4 u) {
    float d = 0.f;
    d = dot2(ph[0], __builtin_bit_cast(f16x2, u.x), d);
    d = dot2(ph[1], __builtin_bit_cast(f16x2, u.y), d);
    d = dot2(ph[2], __builtin_bit_cast(f16x2, u.z), d);
    d = dot2(ph[3], __builtin_bit_cast(f16x2, u.w), d);
    return d;
}

__global__ __launch_bounds__(256) void k_gather(
    const int* __restrict__ ptr, const int* __restrict__ cidx,
    const float* __restrict__ dinv,
    const unsigned char* __restrict__ Ybv, const unsigned short* __restrict__ Ycf,
    const float* __restrict__ att, const float* __restrict__ bias,
    float* __restrict__ out, int N)
{
    int node = blockIdx.x * 4 + (threadIdx.x >> 6);
    if (node >= N) return;
    int lane = threadIdx.x & 63;

    float di = dinv[node];
    float a[8] = {0.f, 0.f, 0.f, 0.f, 0.f, 0.f, 0.f, 0.f};

    // bond: fp8 rows pre-scaled by dinv[c]; accumulate raw, scale by di once.
    {
        uint2 v = *((const uint2*)(Ybv + (size_t)node * 1024) + lane);
        add_q8(a, v, 1.0f);
    }
    {
        int e0 = ptr[node], e1 = ptr[node + 1];
        int e = e0;
        for (; e + 8 <= e1; e += 8) {
            uint2 v[8];
            #pragma unroll
            for (int j = 0; j < 8; j++)
                v[j] = *((const uint2*)(Ybv + (size_t)cidx[e + j] * 1024) + lane);
            #pragma unroll
            for (int j = 0; j < 8; j++) add_q8(a, v[j], 1.0f);
        }
        for (; e < e1; ++e) {
            uint2 v = *((const uint2*)(Ybv + (size_t)cidx[e] * 1024) + lane);
            add_q8(a, v, 1.0f);
        }
    }
    // scale bond partial by di, then add bias
    {
        const float4* bp = (const float4*)(bias + lane * 8);
        float4 q0 = bp[0], q1 = bp[1];
        a[0] = a[0] * di + q0.x; a[1] = a[1] * di + q0.y;
        a[2] = a[2] * di + q0.z; a[3] = a[3] * di + q0.w;
        a[4] = a[4] * di + q1.x; a[5] = a[5] * di + q1.y;
        a[6] = a[6] * di + q1.z; a[7] = a[7] * di + q1.w;
    }
    // vin edges (mean), fp8, chunk-8
    {
        int e0 = ptr[N + node], e1 = ptr[N + node + 1];
        float vsc = 1.0f / (float)((e1 - e0) > 1 ? (e1 - e0) : 1);
        int e = e0;
        for (; e + 8 <= e1; e += 8) {
            uint2 v[8];
            #pragma unroll
            for (int j = 0; j < 8; j++)
                v[j] = *((const uint2*)(Ybv + (size_t)cidx[e + j] * 1024 + 512) + lane);
            #pragma unroll
            for (int j = 0; j < 8; j++) add_q8(a, v[j], vsc);
        }
        for (; e < e1; ++e) {
            uint2 v = *((const uint2*)(Ybv + (size_t)cidx[e] * 1024 + 512) + lane);
            add_q8(a, v, vsc);
        }
    }
    // conn edges (sigmoid dot attention), fp16, chunk-4, packed fdot2
    {
        int e0 = ptr[2 * N + node], e1 = ptr[2 * N + node + 1];
        if (e0 < e1) {
            const float4* ap = (const float4*)att + lane * 2;
            float4 t0 = ap[0], t1 = ap[1];
            float yr[8];
            {
                uint4 u = *((const uint4*)(Ycf + (size_t)node * 512) + lane);
                yr[0] = h2f((unsigned short)(u.x & 0xffff));
                yr[1] = h2f((unsigned short)(u.x >> 16));
                yr[2] = h2f((unsigned short)(u.y & 0xffff));
                yr[3] = h2f((unsigned short)(u.y >> 16));
                yr[4] = h2f((unsigned short)(u.z & 0xffff));
                yr[5] = h2f((unsigned short)(u.z >> 16));
                yr[6] = h2f((unsigned short)(u.w & 0xffff));
                yr[7] = h2f((unsigned short)(u.w >> 16));
            }
            f16x2 ph[4];
            ph[0] = (f16x2){(_Float16)(yr[0] * t0.x * t0.x), (_Float16)(yr[1] * t0.y * t0.y)};
            ph[1] = (f16x2){(_Float16)(yr[2] * t0.z * t0.z), (_Float16)(yr[3] * t0.w * t0.w)};
            ph[2] = (f16x2){(_Float16)(yr[4] * t1.x * t1.x), (_Float16)(yr[5] * t1.y * t1.y)};
            ph[3] = (f16x2){(_Float16)(yr[6] * t1.z * t1.z), (_Float16)(yr[7] * t1.w * t1.w)};
            int e = e0;
            for (; e + 4 <= e1; e += 4) {
                int c0 = cidx[e], c1 = cidx[e + 1], c2 = cidx[e + 2], c3 = cidx[e + 3];
                uint4 u0 = *((const uint4*)(Ycf + (size_t)c0 * 512) + lane);
                uint4 u1 = *((const uint4*)(Ycf + (size_t)c1 * 512) + lane);
                uint4 u2 = *((const uint4*)(Ycf + (size_t)c2 * 512) + lane);
                uint4 u3 = *((const uint4*)(Ycf + (size_t)c3 * 512) + lane);
                float d0 = dot8(ph, u0);
                float d1 = dot8(ph, u1);
                float d2 = dot8(ph, u2);
                float d3 = dot8(ph, u3);
                #pragma unroll
                for (int off = 32; off > 0; off >>= 1) {
                    d0 += __shfl_xor(d0, off);
                    d1 += __shfl_xor(d1, off);
                    d2 += __shfl_xor(d2, off);
                    d3 += __shfl_xor(d3, off);
                }
                float al0 = 1.0f / (1.0f + __expf(-d0));
                float al1 = 1.0f / (1.0f + __expf(-d1));
                float al2 = 1.0f / (1.0f + __expf(-d2));
                float al3 = 1.0f / (1.0f + __expf(-d3));
                acc_h8(a, u0, al0); acc_h8(a, u1, al1);
                acc_h8(a, u2, al2); acc_h8(a, u3, al3);
            }
            for (; e < e1; ++e) {
                int c = cidx[e];
                uint4 u = *((const uint4*)(Ycf + (size_t)c * 512) + lane);
                float dot = dot8(ph, u);
                #pragma unroll
                for (int off = 32; off > 0; off >>= 1) dot += __shfl_xor(dot, off);
                float alpha = 1.0f / (1.0f + __expf(-dot));
                acc_h8(a, u, alpha);
            }
        }
    }
    f32x4 o0 = (f32x4){a[0], a[1], a[2], a[3]};
    f32x4 o1 = (f32x4){a[4], a[5], a[6], a[7]};
    f32x4* dst = (f32x4*)(out + (size_t)node * 512 + lane * 8);
    __builtin_nontemporal_store(o0, dst);
    __builtin_nontemporal_store(o1, dst + 1);
}

extern "C" void kernel_launch(void* const* d_in, const int* in_sizes, int n_in,
                              void* d_out, int out_size, void* d_ws, size_t ws_size,
                              hipStream_t stream) {
    const float* x    = (const float*)d_in[0];
    const int*   eb   = (const int*)d_in[1];
    const int*   ev   = (const int*)d_in[2];
    const int*   ec   = (const int*)d_in[3];
    const float* Wb   = (const float*)d_in[4];
    const float* Wv   = (const float*)d_in[5];
    const float* Wc   = (const float*)d_in[6];
    const float* att  = (const float*)d_in[7];
    const float* bias = (const float*)d_in[8];
    float* out = (float*)d_out;

    const int N  = in_sizes[0] / 512;
    const int Eb = in_sizes[1] / 2;
    const int Ev = in_sizes[2] / 2;
    const int Ec = in_sizes[3] / 2;
    const int Etot = Eb + Ev + Ec;
    const int nbm = (((N + 127) / 128 + 7) / 8) * 8;
    const size_t Npad = (size_t)nbm * 128;
    const int M = 3 * N;
    const int nScanBlocks = (M + 1023) / 1024;

    char* p = (char*)d_ws;
    unsigned char*  Ybv = (unsigned char*)p;  p += Npad * 1024;      // bond(prescaled)|vin fp8
    unsigned short* Ycf = (unsigned short*)p; p += Npad * 512 * 2;   // vconn fp16
    unsigned short* Wf  = (unsigned short*)p; p += (size_t)1536 * 512 * 2;
    unsigned short* xf  = (unsigned short*)p; p += Npad * 512 * 2;
    int* cnt  = (int*)p; p += ((size_t)M * 4 + 255) & ~(size_t)255;
    int* ptr_ = (int*)p; p += ((size_t)(M + 1) * 4 + 255) & ~(size_t)255;
    int* cur  = (int*)p; p += ((size_t)M * 4 + 255) & ~(size_t)255;
    int* bsum = (int*)p; p += 256 * 4;
    int* cidx = (int*)p; p += ((size_t)Etot * 4 + 255) & ~(size_t)255;
    float* dinv = (float*)p; p += ((size_t)N * 4 + 255) & ~(size_t)255;

    const size_t total = Npad * 512, valid = (size_t)N * 512;

    // --- prep (x/W convert + histogram) ---
    hipMemsetAsync(cnt, 0, (size_t)M * 4, stream);
    k_prep<<<(int)((total / 4 + 255) / 256), 256, 0, stream>>>(
        x, xf, valid, total, Wb, Wv, Wc, Wf, eb, ev, ec, Eb, Ev, Ec, cnt, N);

    // --- CSR scans + scatter ---
    k_scan_a<<<nScanBlocks, 256, 0, stream>>>(cnt, ptr_, bsum, M);
    k_scan_c<<<(M + 255) / 256, 256, 0, stream>>>(ptr_, bsum, cur, cnt, dinv, M, N, Etot, nScanBlocks);
    k_scatter3<<<(Etot + 255) / 256, 256, 0, stream>>>(eb, ev, ec, Eb, Ev, Ec, cur, cidx, N);

    // --- GEMM (128x128 tile, A dbuf via gload_lds, B direct from L2) ---
    k_gemm_f<<<nbm * 12, 256, 0, stream>>>(xf, Wf, dinv, N, Ybv, Ycf);

    // --- fused gather ---
    k_gather<<<(N + 3) / 4, 256, 0, stream>>>(ptr_, cidx, dinv, Ybv, Ycf, att, bias, out, N);
}

// Round 18
// 392.681 us; speedup vs baseline: 1.2132x; 1.2132x over previous
//
#include <hip/hip_runtime.h>
#include <hip/hip_fp8.h>
#include <stdint.h>

typedef _Float16 f16x8 __attribute__((ext_vector_type(8)));
typedef _Float16 f16x2 __attribute__((ext_vector_type(2)));
typedef float f32x4 __attribute__((ext_vector_type(4)));
typedef float f32x2 __attribute__((ext_vector_type(2)));

__device__ __forceinline__ unsigned short f2h(float f) {
    _Float16 h = (_Float16)f;
    return __builtin_bit_cast(unsigned short, h);
}
__device__ __forceinline__ float h2f(unsigned short s) {
    _Float16 h = __builtin_bit_cast(_Float16, s);
    return (float)h;
}

// fp8 e4m3 (OCP on gfx950) encode/decode
__device__ __forceinline__ unsigned pack_q4(float f0, float f1, float f2, float f3) {
#if __has_builtin(__builtin_amdgcn_cvt_pk_fp8_f32)
    unsigned u = (unsigned)__builtin_amdgcn_cvt_pk_fp8_f32(f0, f1, 0, false);
    u = (unsigned)__builtin_amdgcn_cvt_pk_fp8_f32(f2, f3, u, true);
    return u;
#else
    __hip_fp8_e4m3 q0(f0), q1(f1), q2(f2), q3(f3);
    return (unsigned)q0.__x | ((unsigned)q1.__x << 8) |
           ((unsigned)q2.__x << 16) | ((unsigned)q3.__x << 24);
#endif
}
__device__ __forceinline__ void add_q8(float* a, uint2 v, float s) {
#if __has_builtin(__builtin_amdgcn_cvt_pk_f32_fp8)
    f32x2 p0 = __builtin_amdgcn_cvt_pk_f32_fp8(v.x, false);
    f32x2 p1 = __builtin_amdgcn_cvt_pk_f32_fp8(v.x, true);
    f32x2 p2 = __builtin_amdgcn_cvt_pk_f32_fp8(v.y, false);
    f32x2 p3 = __builtin_amdgcn_cvt_pk_f32_fp8(v.y, true);
    a[0] += s * p0[0]; a[1] += s * p0[1];
    a[2] += s * p1[0]; a[3] += s * p1[1];
    a[4] += s * p2[0]; a[5] += s * p2[1];
    a[6] += s * p3[0]; a[7] += s * p3[1];
#else
    unsigned char b[8];
    *(uint2*)b = v;
    #pragma unroll
    for (int j = 0; j < 8; j++) {
        __hip_fp8_e4m3 q; q.__x = b[j];
        a[j] += s * (float)q;
    }
#endif
}

__device__ __forceinline__ void gload16(const void* g, void* lds) {
    __builtin_amdgcn_global_load_lds(
        (const __attribute__((address_space(1))) void*)g,
        (__attribute__((address_space(3))) void*)lds, 16, 0, 0);
}

#if __has_builtin(__builtin_amdgcn_fdot2)
__device__ __forceinline__ float dot2(f16x2 a, f16x2 b, float c) {
    return __builtin_amdgcn_fdot2(a, b, c, false);
}
#else
__device__ __forceinline__ float dot2(f16x2 a, f16x2 b, float c) {
    return c + (float)a[0] * (float)b[0] + (float)a[1] * (float)b[1];
}
#endif

// ---------------- fused prep: x f32->fp16 (padded), W stack f32->fp16, edge histogram
__global__ __launch_bounds__(256) void k_prep(
    const float* __restrict__ x, unsigned short* __restrict__ xf,
    size_t valid, size_t total,
    const float* __restrict__ Wb, const float* __restrict__ Wv,
    const float* __restrict__ Wc, unsigned short* __restrict__ Wf,
    const int* __restrict__ eb, const int* __restrict__ ev, const int* __restrict__ ec,
    int Eb, int Ev, int Ec, int* __restrict__ cnt, int N)
{
    size_t i = (size_t)blockIdx.x * 256 + threadIdx.x;
    size_t idx = i * 4;
    if (idx < total) {
        ushort4 h;
        if (idx < valid) {
            float4 f = *(const float4*)(x + idx);
            h.x = f2h(f.x); h.y = f2h(f.y); h.z = f2h(f.z); h.w = f2h(f.w);
        } else {
            h.x = h.y = h.z = h.w = 0;
        }
        *(ushort4*)(xf + idx) = h;
    }
    if (idx < (size_t)1536 * 512) {
        int m = (int)(idx >> 9), k = (int)(idx & 511);
        const float* src;
        if (m < 512)       src = Wb + (size_t)m * 512 + k;
        else if (m < 1024) src = Wv + (size_t)(m - 512) * 512 + k;
        else               src = Wc + (size_t)(m - 1024) * 512 + k;
        float4 f = *(const float4*)src;
        ushort4 h;
        h.x = f2h(f.x); h.y = f2h(f.y); h.z = f2h(f.z); h.w = f2h(f.w);
        *(ushort4*)(Wf + idx) = h;
    }
    if (i < (size_t)(Eb + Ev + Ec)) {
        int ii = (int)i;
        if (ii < Eb) atomicAdd(cnt + eb[ii], 1);
        else if (ii < Eb + Ev) atomicAdd(cnt + N + ev[ii - Eb], 1);
        else atomicAdd(cnt + 2 * N + ec[ii - Eb - Ev], 1);
    }
}

// ---------------- CSR scans / scatter ----------------
__global__ __launch_bounds__(256) void k_scan_a(
    const int* __restrict__ cnt, int* __restrict__ ptr, int* __restrict__ bsum, int M)
{
    __shared__ int sh[256];
    int t = threadIdx.x;
    int base = blockIdx.x * 1024 + t * 4;
    int v[4];
    #pragma unroll
    for (int j = 0; j < 4; j++) v[j] = (base + j < M) ? cnt[base + j] : 0;
    int local = v[0] + v[1] + v[2] + v[3];
    sh[t] = local; __syncthreads();
    #pragma unroll
    for (int off = 1; off < 256; off <<= 1) {
        int x = (t >= off) ? sh[t - off] : 0;
        __syncthreads();
        sh[t] += x;
        __syncthreads();
    }
    int run = sh[t] - local;
    #pragma unroll
    for (int j = 0; j < 4; j++) {
        if (base + j < M) ptr[base + j] = run;
        run += v[j];
    }
    if (t == 255) bsum[blockIdx.x] = sh[255];
}

// scan_c with scan_b folded in: every block redundantly scans bsum (nb<=256)
__global__ __launch_bounds__(256) void k_scan_c(
    int* __restrict__ ptr, const int* __restrict__ bsum, int* __restrict__ cur,
    const int* __restrict__ cnt, float* __restrict__ dinv,
    int M, int N, int total, int nb)
{
    __shared__ int raw[256], scn[256];
    int t = threadIdx.x;
    int v = (t < nb) ? bsum[t] : 0;
    raw[t] = v; scn[t] = v; __syncthreads();
    #pragma unroll
    for (int off = 1; off < 256; off <<= 1) {
        int x = (t >= off) ? scn[t - off] : 0;
        __syncthreads();
        scn[t] += x;
        __syncthreads();
    }
    int idx = blockIdx.x * 256 + t;
    if (idx < M) {
        int blk = idx >> 10;
        int p = ptr[idx] + (scn[blk] - raw[blk]);   // exclusive block offset
        ptr[idx] = p;
        cur[idx] = p;
        if (idx < N) dinv[idx] = rsqrtf((float)(cnt[idx] + 1));
    }
    if (idx == 0) ptr[M] = total;
}

__global__ __launch_bounds__(256) void k_scatter3(
    const int* __restrict__ eb, const int* __restrict__ ev, const int* __restrict__ ec,
    int Eb, int Ev, int Ec, int* __restrict__ cur, int* __restrict__ cidx, int N)
{
    int i = blockIdx.x * 256 + threadIdx.x;
    const int* e; int il, off, E;
    if (i < Eb) { e = eb; il = i; off = 0; E = Eb; }
    else if (i < Eb + Ev) { e = ev; il = i - Eb; off = N; E = Ev; }
    else if (i < Eb + Ev + Ec) { e = ec; il = i - Eb - Ev; off = 2 * N; E = Ec; }
    else return;
    int r = e[il], c = e[E + il];
    int pos = atomicAdd(cur + off + r, 1);
    cidx[pos] = c;
}

// ---------------- UNIFIED fp16 GEMM: 128x128 tile, 4 waves, BK=64,
// dbuf + counted vmcnt. MFMA operands SWAPPED (mfma(b,a)) so the D-row
// dim carries m -> packed 4-wide stores. (R16 configuration, verbatim.)
// bn 0..3 -> Ybv fp8 (bond, PRE-SCALED by dinv[n]); bn 4..7 -> Ybv fp8 (vin);
// bn 8..11 -> Ycf fp16.
__global__ __launch_bounds__(256) void k_gemm_f(
    const unsigned short* __restrict__ xf, const unsigned short* __restrict__ Wf,
    const float* __restrict__ dinv, int N,
    unsigned char* __restrict__ Ybv, unsigned short* __restrict__ Ycf)
{
    __shared__ uint4 As[2][1024];   // 2 x (128 rows x 8 chunks)
    __shared__ uint4 Bs[2][1024];

    const int id = blockIdx.x;
    const int xcd = id & 7;
    const int jj = id >> 3;
    const int bn = jj % 12;
    const int bm = xcd + 8 * (jj / 12);

    const int t = threadIdx.x;
    const int lane = t & 63;
    const int w = t >> 6;            // 0..3
    const int wr = w >> 1;           // 0..1
    const int wc = w & 1;            // 0..1
    const int rA = lane >> 3;        // row within 8-row segment
    const int cs = lane & 7;         // LDS chunk slot

    f32x4 acc[4][4];
    #pragma unroll
    for (int i = 0; i < 4; i++)
        #pragma unroll
        for (int j = 0; j < 4; j++) acc[i][j] = (f32x4){0.f, 0.f, 0.f, 0.f};

    const size_t baseA = (size_t)bm * 128 * 512;
    const size_t baseB = (size_t)bn * 128 * 512;
    const int cg = cs ^ rA;          // pre-swizzled global chunk

    // prologue: stage kt=0 into buffer 0
    #pragma unroll
    for (int j = 0; j < 4; j++) {
        int seg = w * 4 + j;
        int r = seg * 8 + rA;
        gload16(xf + baseA + (size_t)r * 512 + cg * 8, &As[0][seg * 64]);
        gload16(Wf + baseB + (size_t)r * 512 + cg * 8, &Bs[0][seg * 64]);
    }

    int cur = 0;
    for (int step = 0; step < 8; ++step) {
        if (step < 7) {
            int kt = (step + 1) * 64;
            #pragma unroll
            for (int j = 0; j < 4; j++) {
                int seg = w * 4 + j;
                int r = seg * 8 + rA;
                gload16(xf + baseA + (size_t)r * 512 + kt + cg * 8, &As[cur ^ 1][seg * 64]);
                gload16(Wf + baseB + (size_t)r * 512 + kt + cg * 8, &Bs[cur ^ 1][seg * 64]);
            }
            asm volatile("s_waitcnt vmcnt(8)" ::: "memory");
        } else {
            asm volatile("s_waitcnt vmcnt(0)" ::: "memory");
        }
        __builtin_amdgcn_sched_barrier(0);
        __builtin_amdgcn_s_barrier();

        #pragma unroll
        for (int kk = 0; kk < 2; kk++) {
            f16x8 a[4], b[4];
            #pragma unroll
            for (int ni = 0; ni < 4; ni++) {
                int ar = wr * 64 + ni * 16 + (lane & 15);
                int k8 = kk * 4 + (lane >> 4);
                a[ni] = __builtin_bit_cast(f16x8, As[cur][ar * 8 + (k8 ^ (ar & 7))]);
            }
            #pragma unroll
            for (int mi = 0; mi < 4; mi++) {
                int br = wc * 64 + mi * 16 + (lane & 15);
                int k8 = kk * 4 + (lane >> 4);
                b[mi] = __builtin_bit_cast(f16x8, Bs[cur][br * 8 + (k8 ^ (br & 7))]);
            }
            // SWAPPED operands: D rows carry m (b's dim), D cols carry n (a's dim)
            #pragma unroll
            for (int mi = 0; mi < 4; mi++)
                #pragma unroll
                for (int ni = 0; ni < 4; ni++)
                    acc[mi][ni] = __builtin_amdgcn_mfma_f32_16x16x32_f16(
                        b[mi], a[ni], acc[mi][ni], 0, 0, 0);
        }
        asm volatile("s_waitcnt lgkmcnt(0)" ::: "memory");
        __builtin_amdgcn_sched_barrier(0);
        __builtin_amdgcn_s_barrier();
        cur ^= 1;
    }

    // epilogue: n = nbase + ni*16 (lane&15 within tile), m = mq + mi*16 + j
    const int nbase = bm * 128 + wr * 64 + (lane & 15);
    const int mq = wc * 64 + (lane >> 4) * 4;   // m quad base within 128-col tile
    if (bn < 4) {
        #pragma unroll
        for (int ni = 0; ni < 4; ni++) {
            int n = nbase + ni * 16;
            float dv = (n < N) ? dinv[n] : 0.f;
            #pragma unroll
            for (int mi = 0; mi < 4; mi++) {
                int m0 = bn * 128 + mq + mi * 16;
                unsigned u = pack_q4(acc[mi][ni][0] * dv, acc[mi][ni][1] * dv,
                                     acc[mi][ni][2] * dv, acc[mi][ni][3] * dv);
                *(unsigned*)(Ybv + (size_t)n * 1024 + m0) = u;
            }
        }
    } else if (bn < 8) {
        #pragma unroll
        for (int ni = 0; ni < 4; ni++) {
            int n = nbase + ni * 16;
            #pragma unroll
            for (int mi = 0; mi < 4; mi++) {
                int m0 = bn * 128 + mq + mi * 16;
                unsigned u = pack_q4(acc[mi][ni][0], acc[mi][ni][1],
                                     acc[mi][ni][2], acc[mi][ni][3]);
                *(unsigned*)(Ybv + (size_t)n * 1024 + m0) = u;
            }
        }
    } else {
        #pragma unroll
        for (int ni = 0; ni < 4; ni++) {
            int n = nbase + ni * 16;
            #pragma unroll
            for (int mi = 0; mi < 4; mi++) {
                int m0 = (bn - 8) * 128 + mq + mi * 16;
                ushort4 h;
                h.x = f2h(acc[mi][ni][0]); h.y = f2h(acc[mi][ni][1]);
                h.z = f2h(acc[mi][ni][2]); h.w = f2h(acc[mi][ni][3]);
                *(ushort4*)(Ycf + (size_t)n * 512 + m0) = h;
            }
        }
    }
}

// ---------------- fused gather: one wave per node, chunk-4 pipelined (R16 verbatim)
__device__ __forceinline__ void acc_h8(float* a, uint4 v, float s) {
    a[0] += s * h2f((unsigned short)(v.x & 0xffff));
    a[1] += s * h2f((unsigned short)(v.x >> 16));
    a[2] += s * h2f((unsigned short)(v.y & 0xffff));
    a[3] += s * h2f((unsigned short)(v.y >> 16));
    a[4] += s * h2f((unsigned short)(v.z & 0xffff));
    a[5] += s * h2f((unsigned short)(v.z >> 16));
    a[6] += s * h2f((unsigned short)(v.w & 0xffff));
    a[7] += s * h2f((unsigned short)(v.w >> 16));
}
__device__ __forceinline__ float dot8(const f16x2* ph, uint4 u) {
    float d = 0.f;
    d = dot2(ph[0], __builtin_bit_cast(f16x2, u.x), d);
    d = dot2(ph[1], __builtin_bit_cast(f16x2, u.y), d);
    d = dot2(ph[2], __builtin_bit_cast(f16x2, u.z), d);
    d = dot2(ph[3], __builtin_bit_cast(f16x2, u.w), d);
    return d;
}

__global__ __launch_bounds__(256) void k_gather(
    const int* __restrict__ ptr, const int* __restrict__ cidx,
    const float* __restrict__ dinv,
    const unsigned char* __restrict__ Ybv, const unsigned short* __restrict__ Ycf,
    const float* __restrict__ att, const float* __restrict__ bias,
    float* __restrict__ out, int N)
{
    int node = blockIdx.x * 4 + (threadIdx.x >> 6);
    if (node >= N) return;
    int lane = threadIdx.x & 63;

    float di = dinv[node];
    float a[8] = {0.f, 0.f, 0.f, 0.f, 0.f, 0.f, 0.f, 0.f};

    // bond: fp8 rows pre-scaled by dinv[c]; accumulate raw, scale by di once.
    {
        uint2 v = *((const uint2*)(Ybv + (size_t)node * 1024) + lane);
        add_q8(a, v, 1.0f);
    }
    {
        int e0 = ptr[node], e1 = ptr[node + 1];
        int e = e0;
        for (; e + 4 <= e1; e += 4) {
            int c0 = cidx[e], c1 = cidx[e + 1], c2 = cidx[e + 2], c3 = cidx[e + 3];
            uint2 v0 = *((const uint2*)(Ybv + (size_t)c0 * 1024) + lane);
            uint2 v1 = *((const uint2*)(Ybv + (size_t)c1 * 1024) + lane);
            uint2 v2 = *((const uint2*)(Ybv + (size_t)c2 * 1024) + lane);
            uint2 v3 = *((const uint2*)(Ybv + (size_t)c3 * 1024) + lane);
            add_q8(a, v0, 1.0f); add_q8(a, v1, 1.0f);
            add_q8(a, v2, 1.0f); add_q8(a, v3, 1.0f);
        }
        for (; e < e1; ++e) {
            int c = cidx[e];
            uint2 v = *((const uint2*)(Ybv + (size_t)c * 1024) + lane);
            add_q8(a, v, 1.0f);
        }
    }
    // scale bond partial by di, then add bias
    {
        const float4* bp = (const float4*)(bias + lane * 8);
        float4 q0 = bp[0], q1 = bp[1];
        a[0] = a[0] * di + q0.x; a[1] = a[1] * di + q0.y;
        a[2] = a[2] * di + q0.z; a[3] = a[3] * di + q0.w;
        a[4] = a[4] * di + q1.x; a[5] = a[5] * di + q1.y;
        a[6] = a[6] * di + q1.z; a[7] = a[7] * di + q1.w;
    }
    // vin edges (mean), fp8, chunk-4
    {
        int e0 = ptr[N + node], e1 = ptr[N + node + 1];
        float vsc = 1.0f / (float)((e1 - e0) > 1 ? (e1 - e0) : 1);
        int e = e0;
        for (; e + 4 <= e1; e += 4) {
            int c0 = cidx[e], c1 = cidx[e + 1], c2 = cidx[e + 2], c3 = cidx[e + 3];
            uint2 v0 = *((const uint2*)(Ybv + (size_t)c0 * 1024 + 512) + lane);
            uint2 v1 = *((const uint2*)(Ybv + (size_t)c1 * 1024 + 512) + lane);
            uint2 v2 = *((const uint2*)(Ybv + (size_t)c2 * 1024 + 512) + lane);
            uint2 v3 = *((const uint2*)(Ybv + (size_t)c3 * 1024 + 512) + lane);
            add_q8(a, v0, vsc); add_q8(a, v1, vsc);
            add_q8(a, v2, vsc); add_q8(a, v3, vsc);
        }
        for (; e < e1; ++e) {
            int c = cidx[e];
            uint2 v = *((const uint2*)(Ybv + (size_t)c * 1024 + 512) + lane);
            add_q8(a, v, vsc);
        }
    }
    // conn edges (sigmoid dot attention), fp16, chunk-4, packed fdot2
    {
        int e0 = ptr[2 * N + node], e1 = ptr[2 * N + node + 1];
        if (e0 < e1) {
            const float4* ap = (const float4*)att + lane * 2;
            float4 t0 = ap[0], t1 = ap[1];
            float yr[8];
            {
                uint4 u = *((const uint4*)(Ycf + (size_t)node * 512) + lane);
                yr[0] = h2f((unsigned short)(u.x & 0xffff));
                yr[1] = h2f((unsigned short)(u.x >> 16));
                yr[2] = h2f((unsigned short)(u.y & 0xffff));
                yr[3] = h2f((unsigned short)(u.y >> 16));
                yr[4] = h2f((unsigned short)(u.z & 0xffff));
                yr[5] = h2f((unsigned short)(u.z >> 16));
                yr[6] = h2f((unsigned short)(u.w & 0xffff));
                yr[7] = h2f((unsigned short)(u.w >> 16));
            }
            f16x2 ph[4];
            ph[0] = (f16x2){(_Float16)(yr[0] * t0.x * t0.x), (_Float16)(yr[1] * t0.y * t0.y)};
            ph[1] = (f16x2){(_Float16)(yr[2] * t0.z * t0.z), (_Float16)(yr[3] * t0.w * t0.w)};
            ph[2] = (f16x2){(_Float16)(yr[4] * t1.x * t1.x), (_Float16)(yr[5] * t1.y * t1.y)};
            ph[3] = (f16x2){(_Float16)(yr[6] * t1.z * t1.z), (_Float16)(yr[7] * t1.w * t1.w)};
            int e = e0;
            for (; e + 4 <= e1; e += 4) {
                int c0 = cidx[e], c1 = cidx[e + 1], c2 = cidx[e + 2], c3 = cidx[e + 3];
                uint4 u0 = *((const uint4*)(Ycf + (size_t)c0 * 512) + lane);
                uint4 u1 = *((const uint4*)(Ycf + (size_t)c1 * 512) + lane);
                uint4 u2 = *((const uint4*)(Ycf + (size_t)c2 * 512) + lane);
                uint4 u3 = *((const uint4*)(Ycf + (size_t)c3 * 512) + lane);
                float d0 = dot8(ph, u0);
                float d1 = dot8(ph, u1);
                float d2 = dot8(ph, u2);
                float d3 = dot8(ph, u3);
                #pragma unroll
                for (int off = 32; off > 0; off >>= 1) {
                    d0 += __shfl_xor(d0, off);
                    d1 += __shfl_xor(d1, off);
                    d2 += __shfl_xor(d2, off);
                    d3 += __shfl_xor(d3, off);
                }
                float al0 = 1.0f / (1.0f + __expf(-d0));
                float al1 = 1.0f / (1.0f + __expf(-d1));
                float al2 = 1.0f / (1.0f + __expf(-d2));
                float al3 = 1.0f / (1.0f + __expf(-d3));
                acc_h8(a, u0, al0); acc_h8(a, u1, al1);
                acc_h8(a, u2, al2); acc_h8(a, u3, al3);
            }
            for (; e < e1; ++e) {
                int c = cidx[e];
                uint4 u = *((const uint4*)(Ycf + (size_t)c * 512) + lane);
                float dot = dot8(ph, u);
                #pragma unroll
                for (int off = 32; off > 0; off >>= 1) dot += __shfl_xor(dot, off);
                float alpha = 1.0f / (1.0f + __expf(-dot));
                acc_h8(a, u, alpha);
            }
        }
    }
    f32x4 o0 = (f32x4){a[0], a[1], a[2], a[3]};
    f32x4 o1 = (f32x4){a[4], a[5], a[6], a[7]};
    f32x4* dst = (f32x4*)(out + (size_t)node * 512 + lane * 8);
    __builtin_nontemporal_store(o0, dst);
    __builtin_nontemporal_store(o1, dst + 1);
}

extern "C" void kernel_launch(void* const* d_in, const int* in_sizes, int n_in,
                              void* d_out, int out_size, void* d_ws, size_t ws_size,
                              hipStream_t stream) {
    const float* x    = (const float*)d_in[0];
    const int*   eb   = (const int*)d_in[1];
    const int*   ev   = (const int*)d_in[2];
    const int*   ec   = (const int*)d_in[3];
    const float* Wb   = (const float*)d_in[4];
    const float* Wv   = (const float*)d_in[5];
    const float* Wc   = (const float*)d_in[6];
    const float* att  = (const float*)d_in[7];
    const float* bias = (const float*)d_in[8];
    float* out = (float*)d_out;

    const int N  = in_sizes[0] / 512;
    const int Eb = in_sizes[1] / 2;
    const int Ev = in_sizes[2] / 2;
    const int Ec = in_sizes[3] / 2;
    const int Etot = Eb + Ev + Ec;
    const int nbm = (((N + 127) / 128 + 7) / 8) * 8;
    const size_t Npad = (size_t)nbm * 128;
    const int M = 3 * N;
    const int nScanBlocks = (M + 1023) / 1024;

    char* p = (char*)d_ws;
    unsigned char*  Ybv = (unsigned char*)p;  p += Npad * 1024;      // bond(prescaled)|vin fp8
    unsigned short* Ycf = (unsigned short*)p; p += Npad * 512 * 2;   // vconn fp16
    unsigned short* Wf  = (unsigned short*)p; p += (size_t)1536 * 512 * 2;
    unsigned short* xf  = (unsigned short*)p; p += Npad * 512 * 2;
    int* cnt  = (int*)p; p += ((size_t)M * 4 + 255) & ~(size_t)255;
    int* ptr_ = (int*)p; p += ((size_t)(M + 1) * 4 + 255) & ~(size_t)255;
    int* cur  = (int*)p; p += ((size_t)M * 4 + 255) & ~(size_t)255;
    int* bsum = (int*)p; p += 256 * 4;
    int* cidx = (int*)p; p += ((size_t)Etot * 4 + 255) & ~(size_t)255;
    float* dinv = (float*)p; p += ((size_t)N * 4 + 255) & ~(size_t)255;

    const size_t total = Npad * 512, valid = (size_t)N * 512;

    // --- prep (x/W convert + histogram) ---
    hipMemsetAsync(cnt, 0, (size_t)M * 4, stream);
    k_prep<<<(int)((total / 4 + 255) / 256), 256, 0, stream>>>(
        x, xf, valid, total, Wb, Wv, Wc, Wf, eb, ev, ec, Eb, Ev, Ec, cnt, N);

    // --- CSR scans + scatter ---
    k_scan_a<<<nScanBlocks, 256, 0, stream>>>(cnt, ptr_, bsum, M);
    k_scan_c<<<(M + 255) / 256, 256, 0, stream>>>(ptr_, bsum, cur, cnt, dinv, M, N, Etot, nScanBlocks);
    k_scatter3<<<(Etot + 255) / 256, 256, 0, stream>>>(eb, ev, ec, Eb, Ev, Ec, cur, cidx, N);

    // --- GEMM (128x128 tile, dbuf + counted vmcnt, packed epilogue) ---
    k_gemm_f<<<nbm * 12, 256, 0, stream>>>(xf, Wf, dinv, N, Ybv, Ycf);

    // --- fused gather ---
    k_gather<<<(N + 3) / 4, 256, 0, stream>>>(ptr_, cidx, dinv, Ybv, Ycf, att, bias, out, N);
}